// Round 1
// baseline (194.247 us; speedup 1.0000x reference)
//
#include <hip/hip_runtime.h>
#include <math.h>

#define W 32

__global__ __launch_bounds__(256) void qsim_bloch_kernel(
    const float* __restrict__ x,      // [B, 32]
    const float* __restrict__ theta,  // [32, 2]
    const float* __restrict__ w,      // [1,1]
    const float* __restrict__ b,      // [1]
    float* __restrict__ out,          // [B]
    int n)
{
    // Per-block uniform table: (cos ty, sin ty, cos tz, sin tz) per step.
    __shared__ float4 k_tab[W];
    const int tid = threadIdx.x;
    if (tid < W) {
        float ty = theta[tid * 2 + 0];
        float tz = theta[tid * 2 + 1];
        k_tab[tid] = make_float4(cosf(ty), sinf(ty), cosf(tz), sinf(tz));
    }
    __syncthreads();

    const int i = blockIdx.x * blockDim.x + tid;
    if (i >= n) return;

    // Load full row (128 B) as 8 x dwordx4 — all issued before the scan.
    const float4* xr = reinterpret_cast<const float4*>(x + (size_t)i * W);
    float4 xv[8];
#pragma unroll
    for (int j = 0; j < 8; ++j) xv[j] = xr[j];
    const float* xs = reinterpret_cast<const float*>(xv);

    // Bloch vector for |0>
    float rx = 0.0f, ry = 0.0f, rz = 1.0f;

#pragma unroll
    for (int t = 0; t < W; ++t) {
        // RX(x_t): rotate (y,z). v_sin/v_cos take revolutions.
        const float rev = xs[t] * 0.15915494309189535f;  // 1/(2*pi)
        const float sx = __builtin_amdgcn_sinf(rev);
        const float cx = __builtin_amdgcn_cosf(rev);
        const float y1 = cx * ry - sx * rz;
        const float z1 = sx * ry + cx * rz;
        // RY(theta[t,0]): rotate (z,x).  RZ(theta[t,1]): rotate (x,y).
        const float4 k = k_tab[t];  // broadcast read, conflict-free
        const float x1 = k.x * rx + k.y * z1;
        const float z2 = k.x * z1 - k.y * rx;
        rx = k.z * x1 - k.w * y1;
        ry = k.w * x1 + k.z * y1;
        rz = z2;
    }

    out[i] = rz * w[0] + b[0];
}

extern "C" void kernel_launch(void* const* d_in, const int* in_sizes, int n_in,
                              void* d_out, int out_size, void* d_ws, size_t ws_size,
                              hipStream_t stream) {
    const float* x     = (const float*)d_in[0];
    const float* theta = (const float*)d_in[1];
    const float* w     = (const float*)d_in[2];
    const float* b     = (const float*)d_in[3];
    float* out = (float*)d_out;

    const int n = out_size;  // B
    const int block = 256;
    const int grid = (n + block - 1) / block;
    hipLaunchKernelGGL(qsim_bloch_kernel, dim3(grid), dim3(block), 0, stream,
                       x, theta, w, b, out, n);
}